// Round 1
// baseline (6108.833 us; speedup 1.0000x reference)
//
#include <hip/hip_runtime.h>

#define N 4096
#define D 512
#define BIG 1e30f

// ---------------- pdist: dist[i][j] = sqrt(max(sum_k (x[i][k]-x[j][k])^2, 1e-12)), diag = BIG
#define TS 64
#define KT 16

__global__ __launch_bounds__(256) void pdist_kernel(const float* __restrict__ x1,
                                                    const float* __restrict__ x2,
                                                    float* __restrict__ dist1,
                                                    float* __restrict__ dist2) {
    const float* x = (blockIdx.z == 0) ? x1 : x2;
    float* dist = (blockIdx.z == 0) ? dist1 : dist2;
    // +4 pad keeps rows 16B-aligned for float4 LDS reads and breaks pow2 strides
    __shared__ float As[KT][TS + 4];
    __shared__ float Bs[KT][TS + 4];
    const int tid = threadIdx.x;
    const int tx = tid & 15, ty = tid >> 4;
    const int row0 = blockIdx.y * TS, col0 = blockIdx.x * TS;
    float acc[4][4];
#pragma unroll
    for (int i = 0; i < 4; ++i)
#pragma unroll
        for (int j = 0; j < 4; ++j) acc[i][j] = 0.f;

    const int lr = tid >> 2;        // 0..63: row within tile
    const int lk = (tid & 3) * 4;   // 0,4,8,12: k offset

    for (int k0 = 0; k0 < D; k0 += KT) {
        float4 av = *(const float4*)(x + (size_t)(row0 + lr) * D + k0 + lk);
        float4 bv = *(const float4*)(x + (size_t)(col0 + lr) * D + k0 + lk);
        As[lk + 0][lr] = av.x; As[lk + 1][lr] = av.y; As[lk + 2][lr] = av.z; As[lk + 3][lr] = av.w;
        Bs[lk + 0][lr] = bv.x; Bs[lk + 1][lr] = bv.y; Bs[lk + 2][lr] = bv.z; Bs[lk + 3][lr] = bv.w;
        __syncthreads();
#pragma unroll
        for (int kk = 0; kk < KT; ++kk) {
            float4 a4 = *(const float4*)&As[kk][ty * 4];
            float4 b4 = *(const float4*)&Bs[kk][tx * 4];
            float a_[4] = {a4.x, a4.y, a4.z, a4.w};
            float b_[4] = {b4.x, b4.y, b4.z, b4.w};
#pragma unroll
            for (int i = 0; i < 4; ++i)
#pragma unroll
                for (int j = 0; j < 4; ++j) {
                    float dd = a_[i] - b_[j];
                    acc[i][j] = fmaf(dd, dd, acc[i][j]);
                }
        }
        __syncthreads();
    }
#pragma unroll
    for (int i = 0; i < 4; ++i) {
        int row = row0 + ty * 4 + i;
        float4 o;
        float* op = &o.x;
#pragma unroll
        for (int j = 0; j < 4; ++j) {
            int col = col0 + tx * 4 + j;
            float d2 = fmaxf(acc[i][j], 1e-12f);
            op[j] = (row == col) ? BIG : sqrtf(d2);
        }
        *(float4*)(dist + (size_t)row * N + col0 + tx * 4) = o;
    }
}

// ---------------- Prim's MST (exact mirror of the reference lax.scan), 1 block per matrix
__global__ __launch_bounds__(1024) void prim_kernel(const float* __restrict__ dist1,
                                                    float* __restrict__ deaths1,
                                                    const float* __restrict__ dist2,
                                                    float* __restrict__ deaths2) {
    const float* dist = (blockIdx.x == 0) ? dist1 : dist2;
    float* deaths = (blockIdx.x == 0) ? deaths1 : deaths2;
    const int t = threadIdx.x;          // owns indices 4t..4t+3
    const int lane = t & 63, wid = t >> 6;
    __shared__ unsigned long long wmin[16];
    __shared__ unsigned long long wres;

    float4 md = *(const float4*)(dist + 4 * t);   // min_dist := dist[0]
    unsigned tree = (t == 0) ? 1u : 0u;           // in_tree bits for this thread's 4 indices
    if (tree & 1u) md.x = BIG;                    // index 0 masked (diag is BIG anyway)

    for (int iter = 0; iter < N - 1; ++iter) {
        // packed (dist_bits << 32) | idx : min gives argmin with lowest-index tie-break
        unsigned long long b0 = ((unsigned long long)__float_as_uint(md.x) << 32) | (unsigned)(4 * t + 0);
        unsigned long long b1 = ((unsigned long long)__float_as_uint(md.y) << 32) | (unsigned)(4 * t + 1);
        unsigned long long b2 = ((unsigned long long)__float_as_uint(md.z) << 32) | (unsigned)(4 * t + 2);
        unsigned long long b3 = ((unsigned long long)__float_as_uint(md.w) << 32) | (unsigned)(4 * t + 3);
        unsigned long long best = b0 < b1 ? b0 : b1;
        unsigned long long b23 = b2 < b3 ? b2 : b3;
        best = best < b23 ? best : b23;
#pragma unroll
        for (int off = 32; off > 0; off >>= 1) {
            unsigned long long o = __shfl_down(best, off, 64);
            best = o < best ? o : best;
        }
        if (lane == 0) wmin[wid] = best;
        __syncthreads();
        if (t == 0) {
            unsigned long long b = wmin[0];
#pragma unroll
            for (int k = 1; k < 16; ++k) { unsigned long long o = wmin[k]; b = o < b ? o : b; }
            wres = b;
            deaths[iter] = __uint_as_float((unsigned)(b >> 32));
        }
        __syncthreads();
        unsigned long long b = wres;
        int j = (int)(unsigned)b;
        const float4 r = *(const float4*)(dist + (size_t)j * N + 4 * t);
        md.x = fminf(md.x, r.x);
        md.y = fminf(md.y, r.y);
        md.z = fminf(md.z, r.z);
        md.w = fminf(md.w, r.w);
        if ((j >> 2) == t) tree |= 1u << (j & 3);
        if (tree & 1u) md.x = BIG;
        if (tree & 2u) md.y = BIG;
        if (tree & 4u) md.z = BIG;
        if (tree & 8u) md.w = BIG;
    }
}

// ---------------- bitonic sort of 4096 (4095 deaths + one BIG pad) in LDS, 1 block per array
__global__ __launch_bounds__(1024) void sort_kernel(float* __restrict__ deaths1,
                                                    float* __restrict__ deaths2) {
    float* deaths = (blockIdx.x == 0) ? deaths1 : deaths2;
    __shared__ float s[N];
    const int tid = threadIdx.x;
    for (int i = tid; i < N; i += 1024)
        s[i] = (i < N - 1) ? deaths[i] : BIG;
    __syncthreads();
    for (int k = 2; k <= N; k <<= 1) {
        for (int jj = k >> 1; jj > 0; jj >>= 1) {
            for (int t = tid; t < N; t += 1024) {
                int ixj = t ^ jj;
                if (ixj > t) {
                    float a = s[t], b = s[ixj];
                    bool up = ((t & k) == 0);
                    bool sw = up ? (a > b) : (a < b);
                    if (sw) { s[t] = b; s[ixj] = a; }
                }
            }
            __syncthreads();
        }
    }
    for (int i = tid; i < N; i += 1024) deaths[i] = s[i];
}

// ---------------- representation loss: sum (x1-x2)^2, per-wave shuffle + atomicAdd
__global__ void repr_kernel(const float4* __restrict__ a, const float4* __restrict__ b,
                            float* __restrict__ accum) {
    int idx = blockIdx.x * blockDim.x + threadIdx.x;
    int stride = gridDim.x * blockDim.x;
    float s = 0.f;
    for (int i = idx; i < (N * D / 4); i += stride) {
        float4 va = a[i], vb = b[i];
        float dx = va.x - vb.x, dy = va.y - vb.y, dz = va.z - vb.z, dw = va.w - vb.w;
        s = fmaf(dx, dx, s); s = fmaf(dy, dy, s); s = fmaf(dz, dz, s); s = fmaf(dw, dw, s);
    }
#pragma unroll
    for (int off = 32; off > 0; off >>= 1) s += __shfl_down(s, off, 64);
    if ((threadIdx.x & 63) == 0) atomicAdd(accum, s);
}

__global__ void init_kernel(float* __restrict__ accum) {
    if (threadIdx.x == 0) accum[0] = 0.f;
}

// ---------------- final: W1 cost over sorted deaths + L2 term
__global__ __launch_bounds__(1024) void final_kernel(const float* __restrict__ s1,
                                                     const float* __restrict__ s2,
                                                     const float* __restrict__ accum,
                                                     float* __restrict__ out) {
    __shared__ float wsum[16];
    float sum = 0.f;
    for (int i = threadIdx.x; i < N - 1; i += 1024) {
        float a = s1[i], b = s2[i];
        sum += fminf(fabsf(a - b), 0.5f * (a + b));
    }
#pragma unroll
    for (int off = 32; off > 0; off >>= 1) sum += __shfl_down(sum, off, 64);
    int lane = threadIdx.x & 63, wid = threadIdx.x >> 6;
    if (lane == 0) wsum[wid] = sum;
    __syncthreads();
    if (threadIdx.x == 0) {
        float tot = 0.f;
        for (int k = 0; k < 16; ++k) tot += wsum[k];
        out[0] = accum[0] * (1.0f / ((float)N * (float)D)) + tot;
    }
}

extern "C" void kernel_launch(void* const* d_in, const int* in_sizes, int n_in,
                              void* d_out, int out_size, void* d_ws, size_t ws_size,
                              hipStream_t stream) {
    const float* x1 = (const float*)d_in[0];
    const float* x2 = (const float*)d_in[1];
    float* out = (float*)d_out;
    float* ws = (float*)d_ws;

    const size_t nn = (size_t)N * N;
    const size_t need_two = (2 * nn + 2 * N + 64) * sizeof(float);

    if (ws_size >= need_two) {
        // parallel path: both dist matrices live simultaneously
        float* dist1 = ws;
        float* dist2 = dist1 + nn;
        float* deaths1 = dist2 + nn;
        float* deaths2 = deaths1 + N;
        float* accum = deaths2 + N;

        init_kernel<<<1, 64, 0, stream>>>(accum);
        repr_kernel<<<512, 256, 0, stream>>>((const float4*)x1, (const float4*)x2, accum);
        pdist_kernel<<<dim3(N / TS, N / TS, 2), 256, 0, stream>>>(x1, x2, dist1, dist2);
        prim_kernel<<<2, 1024, 0, stream>>>(dist1, deaths1, dist2, deaths2);
        sort_kernel<<<2, 1024, 0, stream>>>(deaths1, deaths2);
        final_kernel<<<1, 1024, 0, stream>>>(deaths1, deaths2, accum, out);
    } else {
        // sequential fallback: one dist buffer, reused
        float* dist = ws;
        float* deaths1 = ws + nn;
        float* deaths2 = deaths1 + N;
        float* accum = deaths2 + N;

        init_kernel<<<1, 64, 0, stream>>>(accum);
        repr_kernel<<<512, 256, 0, stream>>>((const float4*)x1, (const float4*)x2, accum);
        pdist_kernel<<<dim3(N / TS, N / TS, 1), 256, 0, stream>>>(x1, x1, dist, dist);
        prim_kernel<<<1, 1024, 0, stream>>>(dist, deaths1, dist, deaths1);
        pdist_kernel<<<dim3(N / TS, N / TS, 1), 256, 0, stream>>>(x2, x2, dist, dist);
        prim_kernel<<<1, 1024, 0, stream>>>(dist, deaths2, dist, deaths2);
        sort_kernel<<<2, 1024, 0, stream>>>(deaths1, deaths2);
        final_kernel<<<1, 1024, 0, stream>>>(deaths1, deaths2, accum, out);
    }
}

// Round 2
// 1166.255 us; speedup vs baseline: 5.2380x; 5.2380x over previous
//
#include <hip/hip_runtime.h>

#define N 4096
#define D 512
#define BIG 1e30f
#define ROUNDS 12

typedef unsigned long long u64;

// ---------------- pdist: dist[i][j] = sqrt(max(sum_k (x[i][k]-x[j][k])^2, 1e-12)), diag = BIG
#define TS 64
#define KT 16

__global__ __launch_bounds__(256) void pdist_kernel(const float* __restrict__ x1,
                                                    const float* __restrict__ x2,
                                                    float* __restrict__ dist1,
                                                    float* __restrict__ dist2) {
    const float* x = (blockIdx.z == 0) ? x1 : x2;
    float* dist = (blockIdx.z == 0) ? dist1 : dist2;
    __shared__ float As[KT][TS + 4];
    __shared__ float Bs[KT][TS + 4];
    const int tid = threadIdx.x;
    const int tx = tid & 15, ty = tid >> 4;
    const int row0 = blockIdx.y * TS, col0 = blockIdx.x * TS;
    float acc[4][4];
#pragma unroll
    for (int i = 0; i < 4; ++i)
#pragma unroll
        for (int j = 0; j < 4; ++j) acc[i][j] = 0.f;

    const int lr = tid >> 2;
    const int lk = (tid & 3) * 4;

    for (int k0 = 0; k0 < D; k0 += KT) {
        float4 av = *(const float4*)(x + (size_t)(row0 + lr) * D + k0 + lk);
        float4 bv = *(const float4*)(x + (size_t)(col0 + lr) * D + k0 + lk);
        As[lk + 0][lr] = av.x; As[lk + 1][lr] = av.y; As[lk + 2][lr] = av.z; As[lk + 3][lr] = av.w;
        Bs[lk + 0][lr] = bv.x; Bs[lk + 1][lr] = bv.y; Bs[lk + 2][lr] = bv.z; Bs[lk + 3][lr] = bv.w;
        __syncthreads();
#pragma unroll
        for (int kk = 0; kk < KT; ++kk) {
            float4 a4 = *(const float4*)&As[kk][ty * 4];
            float4 b4 = *(const float4*)&Bs[kk][tx * 4];
            float a_[4] = {a4.x, a4.y, a4.z, a4.w};
            float b_[4] = {b4.x, b4.y, b4.z, b4.w};
#pragma unroll
            for (int i = 0; i < 4; ++i)
#pragma unroll
                for (int j = 0; j < 4; ++j) {
                    float dd = a_[i] - b_[j];
                    acc[i][j] = fmaf(dd, dd, acc[i][j]);
                }
        }
        __syncthreads();
    }
#pragma unroll
    for (int i = 0; i < 4; ++i) {
        int row = row0 + ty * 4 + i;
        float4 o;
        float* op = &o.x;
#pragma unroll
        for (int j = 0; j < 4; ++j) {
            int col = col0 + tx * 4 + j;
            float d2 = fmaxf(acc[i][j], 1e-12f);
            op[j] = (row == col) ? BIG : sqrtf(d2);
        }
        *(float4*)(dist + (size_t)row * N + col0 + tx * 4) = o;
    }
}

// ---------------- Boruvka MST ----------------
// state per matrix m: comp[m*N+i], compBest[m*N+c] (packed (w_bits<<32)|j),
// parent/parent2 scratch, deaths[m*N+..], cnt[m], numComp[m]

__global__ void boruvka_init(int* __restrict__ comp, u64* __restrict__ compBest,
                             int* __restrict__ cnt, int* __restrict__ numComp,
                             float* __restrict__ accum) {
    int idx = blockIdx.x * blockDim.x + threadIdx.x;
    if (idx < 2 * N) {
        comp[idx] = idx & (N - 1);
        compBest[idx] = ~0ull;
    }
    if (idx == 0) {
        cnt[0] = 0; cnt[1] = 0;
        numComp[0] = N; numComp[1] = N;
        accum[0] = 0.f;
    }
}

// one block per row: find min edge leaving comp[row], atomicMin into compBest
__global__ __launch_bounds__(256) void boruvka_scan(const float* __restrict__ dist1,
                                                    const float* __restrict__ dist2,
                                                    const int* __restrict__ comp,
                                                    u64* __restrict__ compBest,
                                                    const int* __restrict__ numComp,
                                                    int m0) {
    const int m = m0 + blockIdx.y;
    if (numComp[m] <= 1) return;   // converged: cheap no-op round
    const float* dist = (m == 0) ? dist1 : dist2;
    const int* cp = comp + (size_t)m * N;
    u64* cb = compBest + (size_t)m * N;
    const int r = blockIdx.x;
    const int myc = cp[r];
    const float4* row4 = (const float4*)(dist + (size_t)r * N);
    const int4* cp4 = (const int4*)cp;
    const int t = threadIdx.x;
    u64 best = ~0ull;
#pragma unroll
    for (int k = 0; k < 4; ++k) {
        int c4 = t + 256 * k;
        float4 v = row4[c4];
        int4 cj = cp4[c4];
        int j0 = c4 * 4;
        u64 p0 = (cj.x != myc) ? ((((u64)__float_as_uint(v.x)) << 32) | (unsigned)(j0 + 0)) : ~0ull;
        u64 p1 = (cj.y != myc) ? ((((u64)__float_as_uint(v.y)) << 32) | (unsigned)(j0 + 1)) : ~0ull;
        u64 p2 = (cj.z != myc) ? ((((u64)__float_as_uint(v.z)) << 32) | (unsigned)(j0 + 2)) : ~0ull;
        u64 p3 = (cj.w != myc) ? ((((u64)__float_as_uint(v.w)) << 32) | (unsigned)(j0 + 3)) : ~0ull;
        u64 q0 = p0 < p1 ? p0 : p1;
        u64 q1 = p2 < p3 ? p2 : p3;
        u64 q = q0 < q1 ? q0 : q1;
        best = q < best ? q : best;
    }
#pragma unroll
    for (int off = 32; off > 0; off >>= 1) {
        u64 o = __shfl_down(best, off, 64);
        best = o < best ? o : best;
    }
    if ((t & 63) == 0) atomicMin(cb + myc, best);
}

// one block per matrix: hook components, record deaths, pointer-jump, relabel
__global__ __launch_bounds__(1024) void boruvka_merge(int* __restrict__ comp,
                                                      u64* __restrict__ compBest,
                                                      int* __restrict__ parent,
                                                      int* __restrict__ parent2,
                                                      float* __restrict__ deaths,
                                                      int* __restrict__ cnt,
                                                      int* __restrict__ numComp,
                                                      int m0) {
    const int m = m0 + blockIdx.x;
    if (numComp[m] <= 1) return;
    int* cp = comp + (size_t)m * N;
    u64* cb = compBest + (size_t)m * N;
    int* pa = parent + (size_t)m * N;
    int* pb = parent2 + (size_t)m * N;
    float* dth = deaths + (size_t)m * N;
    const int t = threadIdx.x;

    // hook: parent[c] = target comp; mutual pair keeps smaller id as root.
    // each hook records exactly one MST edge weight (death).
    for (int c = t; c < N; c += 1024) {
        u64 best = cb[c];
        int p = c;
        if (best != ~0ull) {
            int j = (int)(unsigned)best;
            int c2 = cp[j];
            u64 best2 = cb[c2];           // live component always has an out-edge
            int j2 = (int)(unsigned)best2;
            bool mutual = (cp[j2] == c);
            if (!(mutual && c < c2)) {
                p = c2;
                int idx = atomicAdd(cnt + m, 1);
                dth[idx] = __uint_as_float((unsigned)(best >> 32));
            }
        }
        pa[c] = p;
    }
    __syncthreads();

    // pointer jumping, double-buffered; 12 iters covers depth 4096.
    // even # of swaps -> final roots land back in pa.
    for (int it = 0; it < ROUNDS; ++it) {
        for (int c = t; c < N; c += 1024) pb[c] = pa[pa[c]];
        __syncthreads();
        int* tmp = pa; pa = pb; pb = tmp;
    }

    __shared__ unsigned flagbits[N / 32];
    for (int w = t; w < N / 32; w += 1024) flagbits[w] = 0u;
    __syncthreads();
    for (int i = t; i < N; i += 1024) {
        int root = pa[cp[i]];
        cp[i] = root;
        atomicOr(&flagbits[root >> 5], 1u << (root & 31));
    }
    for (int c = t; c < N; c += 1024) cb[c] = ~0ull;  // reset for next round
    __syncthreads();
    if (t < 64) {
        int s = 0;
        for (int w = t; w < N / 32; w += 64) s += __popc(flagbits[w]);
#pragma unroll
        for (int off = 32; off > 0; off >>= 1) s += __shfl_down(s, off, 64);
        if (t == 0) numComp[m] = s;
    }
}

// ---------------- bitonic sort of 4096 (4095 deaths + one BIG pad) in LDS
__global__ __launch_bounds__(1024) void sort_kernel(float* __restrict__ deaths1,
                                                    float* __restrict__ deaths2) {
    float* deaths = (blockIdx.x == 0) ? deaths1 : deaths2;
    __shared__ float s[N];
    const int tid = threadIdx.x;
    for (int i = tid; i < N; i += 1024)
        s[i] = (i < N - 1) ? deaths[i] : BIG;
    __syncthreads();
    for (int k = 2; k <= N; k <<= 1) {
        for (int jj = k >> 1; jj > 0; jj >>= 1) {
            for (int t = tid; t < N; t += 1024) {
                int ixj = t ^ jj;
                if (ixj > t) {
                    float a = s[t], b = s[ixj];
                    bool up = ((t & k) == 0);
                    bool sw = up ? (a > b) : (a < b);
                    if (sw) { s[t] = b; s[ixj] = a; }
                }
            }
            __syncthreads();
        }
    }
    for (int i = tid; i < N; i += 1024) deaths[i] = s[i];
}

// ---------------- representation loss: sum (x1-x2)^2
__global__ void repr_kernel(const float4* __restrict__ a, const float4* __restrict__ b,
                            float* __restrict__ accum) {
    int idx = blockIdx.x * blockDim.x + threadIdx.x;
    int stride = gridDim.x * blockDim.x;
    float s = 0.f;
    for (int i = idx; i < (N * D / 4); i += stride) {
        float4 va = a[i], vb = b[i];
        float dx = va.x - vb.x, dy = va.y - vb.y, dz = va.z - vb.z, dw = va.w - vb.w;
        s = fmaf(dx, dx, s); s = fmaf(dy, dy, s); s = fmaf(dz, dz, s); s = fmaf(dw, dw, s);
    }
#pragma unroll
    for (int off = 32; off > 0; off >>= 1) s += __shfl_down(s, off, 64);
    if ((threadIdx.x & 63) == 0) atomicAdd(accum, s);
}

// ---------------- final: W1 cost over sorted deaths + L2 term
__global__ __launch_bounds__(1024) void final_kernel(const float* __restrict__ s1,
                                                     const float* __restrict__ s2,
                                                     const float* __restrict__ accum,
                                                     float* __restrict__ out) {
    __shared__ float wsum[16];
    float sum = 0.f;
    for (int i = threadIdx.x; i < N - 1; i += 1024) {
        float a = s1[i], b = s2[i];
        sum += fminf(fabsf(a - b), 0.5f * (a + b));
    }
#pragma unroll
    for (int off = 32; off > 0; off >>= 1) sum += __shfl_down(sum, off, 64);
    int lane = threadIdx.x & 63, wid = threadIdx.x >> 6;
    if (lane == 0) wsum[wid] = sum;
    __syncthreads();
    if (threadIdx.x == 0) {
        float tot = 0.f;
        for (int k = 0; k < 16; ++k) tot += wsum[k];
        out[0] = accum[0] * (1.0f / ((float)N * (float)D)) + tot;
    }
}

extern "C" void kernel_launch(void* const* d_in, const int* in_sizes, int n_in,
                              void* d_out, int out_size, void* d_ws, size_t ws_size,
                              hipStream_t stream) {
    const float* x1 = (const float*)d_in[0];
    const float* x2 = (const float*)d_in[1];
    float* out = (float*)d_out;
    float* ws = (float*)d_ws;

    const size_t nn = (size_t)N * N;
    const size_t state_bytes = (size_t)(2 * N) * (8 + 4 + 4 + 4 + 4) + 1024; // compBest+comp+parent+parent2+deaths + counters
    const size_t need_two = 2 * nn * sizeof(float) + state_bytes;

    if (ws_size >= need_two) {
        // parallel path: both dist matrices live simultaneously
        float* dist1 = ws;
        float* dist2 = ws + nn;
        char* base = (char*)(ws + 2 * nn);
        u64* compBest = (u64*)base;
        int* comp     = (int*)(compBest + 2 * N);
        int* parent   = comp + 2 * N;
        int* parent2  = parent + 2 * N;
        float* deaths = (float*)(parent2 + 2 * N);
        int* cnt      = (int*)(deaths + 2 * N);
        int* numComp  = cnt + 2;
        float* accum  = (float*)(numComp + 2);

        boruvka_init<<<(2 * N + 255) / 256, 256, 0, stream>>>(comp, compBest, cnt, numComp, accum);
        repr_kernel<<<512, 256, 0, stream>>>((const float4*)x1, (const float4*)x2, accum);
        pdist_kernel<<<dim3(N / TS, N / TS, 2), 256, 0, stream>>>(x1, x2, dist1, dist2);
        for (int r = 0; r < ROUNDS; ++r) {
            boruvka_scan<<<dim3(N, 2), 256, 0, stream>>>(dist1, dist2, comp, compBest, numComp, 0);
            boruvka_merge<<<2, 1024, 0, stream>>>(comp, compBest, parent, parent2, deaths, cnt, numComp, 0);
        }
        sort_kernel<<<2, 1024, 0, stream>>>(deaths, deaths + N);
        final_kernel<<<1, 1024, 0, stream>>>(deaths, deaths + N, accum, out);
    } else {
        // sequential fallback: one dist buffer, reused for both matrices
        float* dist = ws;
        char* base = (char*)(ws + nn);
        u64* compBest = (u64*)base;
        int* comp     = (int*)(compBest + 2 * N);
        int* parent   = comp + 2 * N;
        int* parent2  = parent + 2 * N;
        float* deaths = (float*)(parent2 + 2 * N);
        int* cnt      = (int*)(deaths + 2 * N);
        int* numComp  = cnt + 2;
        float* accum  = (float*)(numComp + 2);

        boruvka_init<<<(2 * N + 255) / 256, 256, 0, stream>>>(comp, compBest, cnt, numComp, accum);
        repr_kernel<<<512, 256, 0, stream>>>((const float4*)x1, (const float4*)x2, accum);
        pdist_kernel<<<dim3(N / TS, N / TS, 1), 256, 0, stream>>>(x1, x1, dist, dist);
        for (int r = 0; r < ROUNDS; ++r) {
            boruvka_scan<<<dim3(N, 1), 256, 0, stream>>>(dist, dist, comp, compBest, numComp, 0);
            boruvka_merge<<<1, 1024, 0, stream>>>(comp, compBest, parent, parent2, deaths, cnt, numComp, 0);
        }
        pdist_kernel<<<dim3(N / TS, N / TS, 1), 256, 0, stream>>>(x2, x2, dist, dist);
        for (int r = 0; r < ROUNDS; ++r) {
            boruvka_scan<<<dim3(N, 1), 256, 0, stream>>>(dist, dist, comp, compBest, numComp, 1);
            boruvka_merge<<<1, 1024, 0, stream>>>(comp, compBest, parent, parent2, deaths, cnt, numComp, 1);
        }
        sort_kernel<<<2, 1024, 0, stream>>>(deaths, deaths + N);
        final_kernel<<<1, 1024, 0, stream>>>(deaths, deaths + N, accum, out);
    }
}

// Round 3
// 576.701 us; speedup vs baseline: 10.5927x; 2.0223x over previous
//
#include <hip/hip_runtime.h>

#define N 4096
#define D 512
#define BIG 1e30f
#define ROUNDS 12

typedef unsigned long long u64;
typedef unsigned short u16;
typedef __bf16 bf16x8 __attribute__((ext_vector_type(8)));
typedef float floatx4 __attribute__((ext_vector_type(4)));

// ---------------- row squared norms: sq[m*N+row] = sum_k x[row][k]^2
__global__ __launch_bounds__(256) void rowsq_kernel(const float* __restrict__ x1,
                                                    const float* __restrict__ x2,
                                                    float* __restrict__ sq) {
    int m = blockIdx.y;
    const float* x = m ? x2 : x1;
    int wave = threadIdx.x >> 6, lane = threadIdx.x & 63;
    int row = blockIdx.x * 4 + wave;
    const float4* xr = (const float4*)(x + (size_t)row * D);
    float4 a = xr[lane * 2], b = xr[lane * 2 + 1];
    float s = 0.f;
    s = fmaf(a.x, a.x, s); s = fmaf(a.y, a.y, s); s = fmaf(a.z, a.z, s); s = fmaf(a.w, a.w, s);
    s = fmaf(b.x, b.x, s); s = fmaf(b.y, b.y, s); s = fmaf(b.z, b.z, s); s = fmaf(b.w, b.w, s);
#pragma unroll
    for (int off = 32; off > 0; off >>= 1) s += __shfl_down(s, off, 64);
    if (lane == 0) sq[(size_t)m * N + row] = s;
}

// ---------------- dist via bf16-split MFMA GEMM:
// g = hi*hi^T + lo*hi^T + hi*lo^T (hi = trunc-bf16(x), lo = trunc-bf16(x - hi))
// dist[i][j] = sqrt(max(sq_i + sq_j - 2g, 1e-12)), diag = BIG
#define BM 128
#define BN 128
#define BK 32

__global__ __launch_bounds__(256) void gemm_dist_kernel(const float* __restrict__ x1,
                                                        const float* __restrict__ x2,
                                                        const float* __restrict__ sqn,
                                                        float* __restrict__ dist1,
                                                        float* __restrict__ dist2,
                                                        int m0) {
    const int m = m0 + blockIdx.z;
    const float* x = m ? x2 : x1;
    const float* SQ = sqn + (size_t)m * N;
    float* dist = m ? dist2 : dist1;

    __shared__ u16 Ah[BM * BK];   // row-major, 32 u16 = 64B rows
    __shared__ u16 Al[BM * BK];
    __shared__ u16 Bh[BN * BK];
    __shared__ u16 Bl[BN * BK];

    const int tid = threadIdx.x;
    const int wave = tid >> 6, lane = tid & 63;
    const int wm = wave >> 1, wn = wave & 1;
    const int row0 = blockIdx.y * BM, col0 = blockIdx.x * BN;

    floatx4 acc[4][4] = {};

    // staging: thread t owns half-row: row r = t>>1 (0..127), 16 floats at (t&1)*16
    const int sr = tid >> 1;
    const int sh = tid & 1;

    for (int k0 = 0; k0 < D; k0 += BK) {
        __syncthreads();
        // ---- stage A tile (rows row0..row0+127) and B tile (rows col0..col0+127)
        {
            const float4* ga = (const float4*)(x + (size_t)(row0 + sr) * D + k0 + sh * 16);
            const float4* gb = (const float4*)(x + (size_t)(col0 + sr) * D + k0 + sh * 16);
            float4 av[4], bv[4];
#pragma unroll
            for (int q = 0; q < 4; ++q) { av[q] = ga[q]; bv[q] = gb[q]; }
            int hA[8], lA[8], hB[8], lB[8];
#pragma unroll
            for (int q = 0; q < 4; ++q) {
                const float* af = &av[q].x;
                const float* bf = &bv[q].x;
#pragma unroll
                for (int e = 0; e < 2; ++e) {
                    unsigned u0 = __float_as_uint(af[2 * e]);
                    unsigned u1 = __float_as_uint(af[2 * e + 1]);
                    hA[q * 2 + e] = (int)((u0 >> 16) | (u1 & 0xffff0000u));
                    float l0 = af[2 * e] - __uint_as_float(u0 & 0xffff0000u);
                    float l1 = af[2 * e + 1] - __uint_as_float(u1 & 0xffff0000u);
                    lA[q * 2 + e] = (int)((__float_as_uint(l0) >> 16) | (__float_as_uint(l1) & 0xffff0000u));
                    unsigned w0 = __float_as_uint(bf[2 * e]);
                    unsigned w1 = __float_as_uint(bf[2 * e + 1]);
                    hB[q * 2 + e] = (int)((w0 >> 16) | (w1 & 0xffff0000u));
                    float m0_ = bf[2 * e] - __uint_as_float(w0 & 0xffff0000u);
                    float m1_ = bf[2 * e + 1] - __uint_as_float(w1 & 0xffff0000u);
                    lB[q * 2 + e] = (int)((__float_as_uint(m0_) >> 16) | (__float_as_uint(m1_) & 0xffff0000u));
                }
            }
            int* dAh = (int*)(Ah + sr * BK + sh * 16);
            int* dAl = (int*)(Al + sr * BK + sh * 16);
            int* dBh = (int*)(Bh + sr * BK + sh * 16);
            int* dBl = (int*)(Bl + sr * BK + sh * 16);
            *(int4*)(dAh) = make_int4(hA[0], hA[1], hA[2], hA[3]);
            *(int4*)(dAh + 4) = make_int4(hA[4], hA[5], hA[6], hA[7]);
            *(int4*)(dAl) = make_int4(lA[0], lA[1], lA[2], lA[3]);
            *(int4*)(dAl + 4) = make_int4(lA[4], lA[5], lA[6], lA[7]);
            *(int4*)(dBh) = make_int4(hB[0], hB[1], hB[2], hB[3]);
            *(int4*)(dBh + 4) = make_int4(hB[4], hB[5], hB[6], hB[7]);
            *(int4*)(dBl) = make_int4(lB[0], lB[1], lB[2], lB[3]);
            *(int4*)(dBl + 4) = make_int4(lB[4], lB[5], lB[6], lB[7]);
        }
        __syncthreads();

        // ---- fragments: A[m=lane&15][k=(lane>>4)*8+j]
        const int fo = (lane >> 4) * 8;
        const int fm = lane & 15;
        bf16x8 ah[4], al[4], bh[4], bl[4];
#pragma unroll
        for (int s = 0; s < 4; ++s) {
            ah[s] = *(bf16x8*)(Ah + (wm * 64 + s * 16 + fm) * BK + fo);
            al[s] = *(bf16x8*)(Al + (wm * 64 + s * 16 + fm) * BK + fo);
            bh[s] = *(bf16x8*)(Bh + (wn * 64 + s * 16 + fm) * BK + fo);
            bl[s] = *(bf16x8*)(Bl + (wn * 64 + s * 16 + fm) * BK + fo);
        }
#pragma unroll
        for (int i = 0; i < 4; ++i)
#pragma unroll
            for (int j = 0; j < 4; ++j) {
                acc[i][j] = __builtin_amdgcn_mfma_f32_16x16x32_bf16(ah[i], bh[j], acc[i][j], 0, 0, 0);
                acc[i][j] = __builtin_amdgcn_mfma_f32_16x16x32_bf16(al[i], bh[j], acc[i][j], 0, 0, 0);
                acc[i][j] = __builtin_amdgcn_mfma_f32_16x16x32_bf16(ah[i], bl[j], acc[i][j], 0, 0, 0);
            }
    }

    // ---- epilogue: C layout col=lane&15, row=(lane>>4)*4+reg
    const int lr = lane & 15;
    const int lq = lane >> 4;
    float sc[4];
#pragma unroll
    for (int ns = 0; ns < 4; ++ns) sc[ns] = SQ[col0 + wn * 64 + ns * 16 + lr];
#pragma unroll
    for (int ms = 0; ms < 4; ++ms) {
        const int rb = row0 + wm * 64 + ms * 16 + lq * 4;
        float srow[4];
#pragma unroll
        for (int r = 0; r < 4; ++r) srow[r] = SQ[rb + r];
#pragma unroll
        for (int ns = 0; ns < 4; ++ns) {
            const int col = col0 + wn * 64 + ns * 16 + lr;
#pragma unroll
            for (int r = 0; r < 4; ++r) {
                const int row = rb + r;
                float d2 = srow[r] + sc[ns] - 2.0f * acc[ms][ns][r];
                float dv = (row == col) ? BIG : sqrtf(fmaxf(d2, 1e-12f));
                dist[(size_t)row * N + col] = dv;
            }
        }
    }
}

// ---------------- Boruvka MST ----------------
__global__ void boruvka_init(int* __restrict__ comp, u64* __restrict__ compBest,
                             int* __restrict__ cnt, int* __restrict__ numComp,
                             float* __restrict__ accum) {
    int idx = blockIdx.x * blockDim.x + threadIdx.x;
    if (idx < 2 * N) {
        comp[idx] = idx & (N - 1);
        compBest[idx] = ~0ull;
    }
    if (idx == 0) {
        cnt[0] = 0; cnt[1] = 0;
        numComp[0] = N; numComp[1] = N;
        accum[0] = 0.f;
    }
}

__global__ __launch_bounds__(256) void boruvka_scan(const float* __restrict__ dist1,
                                                    const float* __restrict__ dist2,
                                                    const int* __restrict__ comp,
                                                    u64* __restrict__ compBest,
                                                    const int* __restrict__ numComp,
                                                    int m0) {
    const int m = m0 + blockIdx.y;
    if (numComp[m] <= 1) return;
    const float* dist = (m == 0) ? dist1 : dist2;
    const int* cp = comp + (size_t)m * N;
    u64* cb = compBest + (size_t)m * N;
    const int r = blockIdx.x;
    const int myc = cp[r];
    const float4* row4 = (const float4*)(dist + (size_t)r * N);
    const int4* cp4 = (const int4*)cp;
    const int t = threadIdx.x;
    u64 best = ~0ull;
#pragma unroll
    for (int k = 0; k < 4; ++k) {
        int c4 = t + 256 * k;
        float4 v = row4[c4];
        int4 cj = cp4[c4];
        int j0 = c4 * 4;
        u64 p0 = (cj.x != myc) ? ((((u64)__float_as_uint(v.x)) << 32) | (unsigned)(j0 + 0)) : ~0ull;
        u64 p1 = (cj.y != myc) ? ((((u64)__float_as_uint(v.y)) << 32) | (unsigned)(j0 + 1)) : ~0ull;
        u64 p2 = (cj.z != myc) ? ((((u64)__float_as_uint(v.z)) << 32) | (unsigned)(j0 + 2)) : ~0ull;
        u64 p3 = (cj.w != myc) ? ((((u64)__float_as_uint(v.w)) << 32) | (unsigned)(j0 + 3)) : ~0ull;
        u64 q0 = p0 < p1 ? p0 : p1;
        u64 q1 = p2 < p3 ? p2 : p3;
        u64 q = q0 < q1 ? q0 : q1;
        best = q < best ? q : best;
    }
#pragma unroll
    for (int off = 32; off > 0; off >>= 1) {
        u64 o = __shfl_down(best, off, 64);
        best = o < best ? o : best;
    }
    if ((t & 63) == 0) atomicMin(cb + myc, best);
}

// hook + adaptive LDS pointer-jumping + relabel
__global__ __launch_bounds__(1024) void boruvka_merge(int* __restrict__ comp,
                                                      u64* __restrict__ compBest,
                                                      float* __restrict__ deaths,
                                                      int* __restrict__ cnt,
                                                      int* __restrict__ numComp,
                                                      int m0) {
    const int m = m0 + blockIdx.x;
    if (numComp[m] <= 1) return;
    int* cp = comp + (size_t)m * N;
    u64* cb = compBest + (size_t)m * N;
    float* dth = deaths + (size_t)m * N;
    const int t = threadIdx.x;
    __shared__ int pa[N];
    __shared__ int pb[N];
    __shared__ int done;
    __shared__ unsigned flagbits[N / 32];

    for (int c = t; c < N; c += 1024) {
        u64 best = cb[c];
        int p = c;
        if (best != ~0ull) {
            int j = (int)(unsigned)best;
            int c2 = cp[j];
            u64 best2 = cb[c2];
            int j2 = (int)(unsigned)best2;
            bool mutual = (cp[j2] == c);
            if (!(mutual && c < c2)) {
                p = c2;
                int idx = atomicAdd(cnt + m, 1);
                dth[idx] = __uint_as_float((unsigned)(best >> 32));
            }
        }
        pa[c] = p;
    }

    int* A = pa;
    int* B = pb;
    while (true) {
        __syncthreads();
        if (t == 0) done = 1;
        __syncthreads();
        bool ch = false;
        for (int c = t; c < N; c += 1024) {
            int g = A[A[c]];
            B[c] = g;
            ch |= (g != A[c]);
        }
        if (ch) done = 0;
        __syncthreads();
        int* tmp = A; A = B; B = tmp;
        if (done) break;
    }

    for (int w = t; w < N / 32; w += 1024) flagbits[w] = 0u;
    __syncthreads();
    for (int i = t; i < N; i += 1024) {
        int root = A[cp[i]];
        cp[i] = root;
        atomicOr(&flagbits[root >> 5], 1u << (root & 31));
    }
    for (int c = t; c < N; c += 1024) cb[c] = ~0ull;
    __syncthreads();
    if (t < 64) {
        int s = 0;
        for (int w = t; w < N / 32; w += 64) s += __popc(flagbits[w]);
#pragma unroll
        for (int off = 32; off > 0; off >>= 1) s += __shfl_down(s, off, 64);
        if (t == 0) numComp[m] = s;
    }
}

// ---------------- bitonic sort of 4096 (4095 deaths + one BIG pad) in LDS
__global__ __launch_bounds__(1024) void sort_kernel(float* __restrict__ deaths1,
                                                    float* __restrict__ deaths2) {
    float* deaths = (blockIdx.x == 0) ? deaths1 : deaths2;
    __shared__ float s[N];
    const int tid = threadIdx.x;
    for (int i = tid; i < N; i += 1024)
        s[i] = (i < N - 1) ? deaths[i] : BIG;
    __syncthreads();
    for (int k = 2; k <= N; k <<= 1) {
        for (int jj = k >> 1; jj > 0; jj >>= 1) {
            for (int t = tid; t < N; t += 1024) {
                int ixj = t ^ jj;
                if (ixj > t) {
                    float a = s[t], b = s[ixj];
                    bool up = ((t & k) == 0);
                    bool sw = up ? (a > b) : (a < b);
                    if (sw) { s[t] = b; s[ixj] = a; }
                }
            }
            __syncthreads();
        }
    }
    for (int i = tid; i < N; i += 1024) deaths[i] = s[i];
}

// ---------------- representation loss: sum (x1-x2)^2
__global__ void repr_kernel(const float4* __restrict__ a, const float4* __restrict__ b,
                            float* __restrict__ accum) {
    int idx = blockIdx.x * blockDim.x + threadIdx.x;
    int stride = gridDim.x * blockDim.x;
    float s = 0.f;
    for (int i = idx; i < (N * D / 4); i += stride) {
        float4 va = a[i], vb = b[i];
        float dx = va.x - vb.x, dy = va.y - vb.y, dz = va.z - vb.z, dw = va.w - vb.w;
        s = fmaf(dx, dx, s); s = fmaf(dy, dy, s); s = fmaf(dz, dz, s); s = fmaf(dw, dw, s);
    }
#pragma unroll
    for (int off = 32; off > 0; off >>= 1) s += __shfl_down(s, off, 64);
    if ((threadIdx.x & 63) == 0) atomicAdd(accum, s);
}

// ---------------- final: W1 cost over sorted deaths + L2 term
__global__ __launch_bounds__(1024) void final_kernel(const float* __restrict__ s1,
                                                     const float* __restrict__ s2,
                                                     const float* __restrict__ accum,
                                                     float* __restrict__ out) {
    __shared__ float wsum[16];
    float sum = 0.f;
    for (int i = threadIdx.x; i < N - 1; i += 1024) {
        float a = s1[i], b = s2[i];
        sum += fminf(fabsf(a - b), 0.5f * (a + b));
    }
#pragma unroll
    for (int off = 32; off > 0; off >>= 1) sum += __shfl_down(sum, off, 64);
    int lane = threadIdx.x & 63, wid = threadIdx.x >> 6;
    if (lane == 0) wsum[wid] = sum;
    __syncthreads();
    if (threadIdx.x == 0) {
        float tot = 0.f;
        for (int k = 0; k < 16; ++k) tot += wsum[k];
        out[0] = accum[0] * (1.0f / ((float)N * (float)D)) + tot;
    }
}

extern "C" void kernel_launch(void* const* d_in, const int* in_sizes, int n_in,
                              void* d_out, int out_size, void* d_ws, size_t ws_size,
                              hipStream_t stream) {
    const float* x1 = (const float*)d_in[0];
    const float* x2 = (const float*)d_in[1];
    float* out = (float*)d_out;
    float* ws = (float*)d_ws;

    const size_t nn = (size_t)N * N;
    // state after dist buffers: compBest(2N u64) comp(2N) deaths(2N) cnt/numComp/accum sq(2N)
    const size_t state_floats = 2 * N * 2 /*compBest*/ + 2 * N + 2 * N + 8 + 2 * N;
    const size_t need_two = (2 * nn + state_floats) * sizeof(float);
    const size_t need_one = (nn + state_floats) * sizeof(float);

    if (ws_size >= need_two) {
        float* dist1 = ws;
        float* dist2 = ws + nn;
        u64* compBest = (u64*)(ws + 2 * nn);
        int* comp     = (int*)(compBest + 2 * N);
        float* deaths = (float*)(comp + 2 * N);
        int* cnt      = (int*)(deaths + 2 * N);
        int* numComp  = cnt + 2;
        float* accum  = (float*)(numComp + 2);
        float* sq     = accum + 2;

        boruvka_init<<<(2 * N + 255) / 256, 256, 0, stream>>>(comp, compBest, cnt, numComp, accum);
        rowsq_kernel<<<dim3(N / 4, 2), 256, 0, stream>>>(x1, x2, sq);
        repr_kernel<<<512, 256, 0, stream>>>((const float4*)x1, (const float4*)x2, accum);
        gemm_dist_kernel<<<dim3(N / BN, N / BM, 2), 256, 0, stream>>>(x1, x2, sq, dist1, dist2, 0);
        for (int r = 0; r < ROUNDS; ++r) {
            boruvka_scan<<<dim3(N, 2), 256, 0, stream>>>(dist1, dist2, comp, compBest, numComp, 0);
            boruvka_merge<<<2, 1024, 0, stream>>>(comp, compBest, deaths, cnt, numComp, 0);
        }
        sort_kernel<<<2, 1024, 0, stream>>>(deaths, deaths + N);
        final_kernel<<<1, 1024, 0, stream>>>(deaths, deaths + N, accum, out);
    } else {
        (void)need_one;
        float* dist = ws;
        u64* compBest = (u64*)(ws + nn);
        int* comp     = (int*)(compBest + 2 * N);
        float* deaths = (float*)(comp + 2 * N);
        int* cnt      = (int*)(deaths + 2 * N);
        int* numComp  = cnt + 2;
        float* accum  = (float*)(numComp + 2);
        float* sq     = accum + 2;

        boruvka_init<<<(2 * N + 255) / 256, 256, 0, stream>>>(comp, compBest, cnt, numComp, accum);
        rowsq_kernel<<<dim3(N / 4, 2), 256, 0, stream>>>(x1, x2, sq);
        repr_kernel<<<512, 256, 0, stream>>>((const float4*)x1, (const float4*)x2, accum);
        gemm_dist_kernel<<<dim3(N / BN, N / BM, 1), 256, 0, stream>>>(x1, x2, sq, dist, dist, 0);
        for (int r = 0; r < ROUNDS; ++r) {
            boruvka_scan<<<dim3(N, 1), 256, 0, stream>>>(dist, dist, comp, compBest, numComp, 0);
            boruvka_merge<<<1, 1024, 0, stream>>>(comp, compBest, deaths, cnt, numComp, 0);
        }
        gemm_dist_kernel<<<dim3(N / BN, N / BM, 1), 256, 0, stream>>>(x1, x2, sq, dist, dist, 1);
        for (int r = 0; r < ROUNDS; ++r) {
            boruvka_scan<<<dim3(N, 1), 256, 0, stream>>>(dist, dist, comp, compBest, numComp, 1);
            boruvka_merge<<<1, 1024, 0, stream>>>(comp, compBest, deaths, cnt, numComp, 1);
        }
        sort_kernel<<<2, 1024, 0, stream>>>(deaths, deaths + N);
        final_kernel<<<1, 1024, 0, stream>>>(deaths, deaths + N, accum, out);
    }
}